// Round 8
// baseline (311.372 us; speedup 1.0000x reference)
//
#include <hip/hip_runtime.h>
#include <math.h>

namespace {
constexpr int B_ = 32, S_ = 1024, D_ = 256, N_ = 32, C_ = 64;
constexpr int NC_ = N_ * C_;  // 2048
constexpr int XP_ = 16;       // chunks (and xsum partials) per b

typedef __bf16 bf16x8 __attribute__((ext_vector_type(8)));
typedef __bf16 bf16x4 __attribute__((ext_vector_type(4)));
typedef float floatx4 __attribute__((ext_vector_type(4)));

constexpr int XS_ = 264;  // x_lds row stride
constexpr int CS_ = 72;   // c_T row stride (s 64 + 8 pad)
}  // namespace

// ---- per-b producer/consumer sync (device-scope, XCD-safe) ----
__device__ __forceinline__ void arrive(int* p) {
  __syncthreads();  // all block threads' writes drained (vmcnt) before release
  if (threadIdx.x == 0)
    __hip_atomic_fetch_add(p, 1, __ATOMIC_ACQ_REL, __HIP_MEMORY_SCOPE_AGENT);
}
__device__ __forceinline__ void wait16(int* p) {
  if (threadIdx.x == 0) {
    while (__hip_atomic_load(p, __ATOMIC_ACQUIRE, __HIP_MEMORY_SCOPE_AGENT) < 16)
      __builtin_amdgcn_s_sleep(2);
  }
  __syncthreads();
}

// ---- one (b,n) small unit; zloc (256 fl) preloaded in LDS ----
__device__ __forceinline__ void small_one(
    int b, int n, const float* __restrict__ W, float scale, int accum,
    int final_, float* __restrict__ t_fp, __bf16* __restrict__ t_bhi,
    __bf16* __restrict__ t_blo, float* __restrict__ out,
    const float* zloc, float* sq_red, float* v_lds) {
  const int t = threadIdx.x;
  const int c = t & 63, dq = t >> 6;
  const float* Wn = W + (size_t)n * (D_ * C_);
  float s = 0.f;
  #pragma unroll 8
  for (int dd = 0; dd < 64; ++dd) {
    int d = dq * 64 + dd;
    s += zloc[d] * Wn[d * 64 + c];
  }
  sq_red[dq * 64 + c] = s;
  __syncthreads();
  if (t < 64) {
    float sc = (sq_red[t] + sq_red[64 + t] + sq_red[128 + t] + sq_red[192 + t]) * scale;
    float sq = sc * sc;
    #pragma unroll
    for (int m = 1; m <= 32; m <<= 1) sq += __shfl_xor(sq, m);
    float scl = sq / ((1.f + sq) * sqrtf(sq + 1e-8f));
    float v = sc * scl;
    v_lds[t] = v;
    if (final_) out[(size_t)b * NC_ + n * 64 + t] = v;
  }
  __syncthreads();
  if (!final_) {
    const float4* W4 = (const float4*)Wn + t * 16;
    float acc = 0.f;
    #pragma unroll
    for (int q = 0; q < 16; ++q) {
      float4 wv = W4[q];
      acc += wv.x * v_lds[q * 4] + wv.y * v_lds[q * 4 + 1] +
             wv.z * v_lds[q * 4 + 2] + wv.w * v_lds[q * 4 + 3];
    }
    size_t idx = ((size_t)b * N_ + n) * D_ + t;
    float tf = acc + (accum ? t_fp[idx] : 0.f);
    t_fp[idx] = tf;
    __bf16 hi = (__bf16)tf;
    t_bhi[idx] = hi;
    t_blo[idx] = (__bf16)(tf - (float)hi);
  }
  __syncthreads();
}

// ---- routing pass: agr = x.t (t hi/lo from global/L2) -> softmax -> y += c^T@x ----
__device__ __forceinline__ void pass_phase(
    int b, const __bf16* __restrict__ t_bhi, const __bf16* __restrict__ t_blo,
    float* __restrict__ y, const __bf16* x_lds, __bf16* c_Th, __bf16* c_Tl) {
  const int t = threadIdx.x, w = t >> 6, lane = t & 63;
  const int quad = lane >> 4, l16 = lane & 15;
  const __bf16* tb_h = t_bhi + (size_t)b * 8192;
  const __bf16* tb_l = t_blo + (size_t)b * 8192;

  floatx4 acc[2];
  acc[0] = (floatx4){0.f, 0.f, 0.f, 0.f};
  acc[1] = (floatx4){0.f, 0.f, 0.f, 0.f};
  const int sbase = w * 16;
  #pragma unroll
  for (int k0 = 0; k0 < 256; k0 += 32) {
    int ks = k0 + quad * 8;
    bf16x8 bfrag = *(const bf16x8*)(x_lds + (sbase + l16) * XS_ + ks);
    #pragma unroll
    for (int i = 0; i < 2; ++i) {
      bf16x8 ah = *(const bf16x8*)(tb_h + (i * 16 + l16) * 256 + ks);
      bf16x8 al = *(const bf16x8*)(tb_l + (i * 16 + l16) * 256 + ks);
      acc[i] = __builtin_amdgcn_mfma_f32_16x16x32_bf16(ah, bfrag, acc[i], 0, 0, 0);
      acc[i] = __builtin_amdgcn_mfma_f32_16x16x32_bf16(al, bfrag, acc[i], 0, 0, 0);
    }
  }
  float mx = -1e30f;
  #pragma unroll
  for (int i = 0; i < 2; ++i)
    #pragma unroll
    for (int r = 0; r < 4; ++r) mx = fmaxf(mx, acc[i][r]);
  mx = fmaxf(mx, __shfl_xor(mx, 16));
  mx = fmaxf(mx, __shfl_xor(mx, 32));
  float e_[2][4];
  float ss = 0.f;
  #pragma unroll
  for (int i = 0; i < 2; ++i)
    #pragma unroll
    for (int r = 0; r < 4; ++r) { e_[i][r] = __expf(acc[i][r] - mx); ss += e_[i][r]; }
  ss += __shfl_xor(ss, 16);
  ss += __shfl_xor(ss, 32);
  float inv = 1.f / ss;
  #pragma unroll
  for (int i = 0; i < 2; ++i)
    #pragma unroll
    for (int r = 0; r < 4; ++r) {
      float cv = e_[i][r] * inv;
      __bf16 chi = (__bf16)cv;
      int o = (i * 16 + quad * 4 + r) * CS_ + sbase + l16;
      c_Th[o] = chi;
      c_Tl[o] = (__bf16)(cv - (float)chi);
    }
  __syncthreads();

  floatx4 acc2[2][4];
  #pragma unroll
  for (int i = 0; i < 2; ++i)
    #pragma unroll
    for (int dt = 0; dt < 4; ++dt) acc2[i][dt] = (floatx4){0.f, 0.f, 0.f, 0.f};
  const int dbase = w * 64;
  #pragma unroll
  for (int k0 = 0; k0 < 64; k0 += 32) {
    int ks = k0 + quad * 8;
    bf16x8 ah[2], al[2];
    #pragma unroll
    for (int i = 0; i < 2; ++i) {
      ah[i] = *(const bf16x8*)(c_Th + (i * 16 + l16) * CS_ + ks);
      al[i] = *(const bf16x8*)(c_Tl + (i * 16 + l16) * CS_ + ks);
    }
    #pragma unroll
    for (int dt = 0; dt < 4; ++dt) {
      bf16x8 bfr;
      #pragma unroll
      for (int j8 = 0; j8 < 8; ++j8)
        bfr[j8] = x_lds[(ks + j8) * XS_ + dbase + dt * 16 + l16];
      #pragma unroll
      for (int i = 0; i < 2; ++i) {
        acc2[i][dt] = __builtin_amdgcn_mfma_f32_16x16x32_bf16(ah[i], bfr, acc2[i][dt], 0, 0, 0);
        acc2[i][dt] = __builtin_amdgcn_mfma_f32_16x16x32_bf16(al[i], bfr, acc2[i][dt], 0, 0, 0);
      }
    }
  }
  #pragma unroll
  for (int i = 0; i < 2; ++i)
    #pragma unroll
    for (int dt = 0; dt < 4; ++dt)
      #pragma unroll
      for (int r = 0; r < 4; ++r) {
        int n = i * 16 + quad * 4 + r;
        int d = dbase + dt * 16 + l16;
        atomicAdd(&y[((size_t)b * N_ + n) * D_ + d], acc2[i][dt][r]);
      }
  __syncthreads();
}

// ---- whole pipeline, one launch: 512 blocks = (b, ch); per-b sync only ----
extern "C" __global__ __launch_bounds__(256) void k_fused(
    const float* __restrict__ x, const float* __restrict__ W,
    float* __restrict__ xsum_part, float* __restrict__ y1,
    float* __restrict__ y2, float* __restrict__ t_fp,
    __bf16* __restrict__ t_bhi, __bf16* __restrict__ t_blo,
    int* __restrict__ cnt, float* __restrict__ out) {
  __shared__ __align__(16) __bf16 x_lds[64 * XS_];  // 33,792 B, lives all phases
  __shared__ __align__(16) __bf16 c_Th[N_ * CS_];   //  4,608 B
  __shared__ __align__(16) __bf16 c_Tl[N_ * CS_];   //  4,608 B  (total 43,008)
  float* zloc = (float*)c_Th;          // aliases, used only in small phases
  float* sq_red = (float*)c_Th + 256;
  float* v_lds = (float*)c_Th + 512;
  float* ph0red = (float*)c_Tl;        // 4 KB, ph0 only

  const int bidx = blockIdx.x;
  const int b = bidx >> 4, ch = bidx & 15;
  const int t = threadIdx.x;
  int* c0 = cnt + b;          // ph0 done
  int* ct1 = cnt + 32 + b;    // t1 ready
  int* cy1 = cnt + 64 + b;    // y1 done
  int* ct2 = cnt + 96 + b;    // t12 ready
  int* cy2 = cnt + 128 + b;   // y2 done

  // ---- ph0: stage x chunk -> LDS bf16, xsum partial, zero y1/y2 slices ----
  {
    const float* xb = x + ((size_t)b * S_ + ch * 64) * D_;
    float xp[4] = {0.f, 0.f, 0.f, 0.f};
    #pragma unroll
    for (int i = 0; i < 16; ++i) {
      int pos = i * 1024 + t * 4;
      int row = pos >> 8, col = (t & 63) * 4;
      float4 f = *(const float4*)(xb + pos);
      bf16x4 p4;
      p4[0] = (__bf16)f.x; p4[1] = (__bf16)f.y;
      p4[2] = (__bf16)f.z; p4[3] = (__bf16)f.w;
      *(bf16x4*)(x_lds + row * XS_ + col) = p4;
      xp[0] += f.x; xp[1] += f.y; xp[2] += f.z; xp[3] += f.w;
    }
    const int w = t >> 6, col = (t & 63) * 4;
    #pragma unroll
    for (int k = 0; k < 4; ++k) ph0red[w * 256 + col + k] = xp[k];
    __syncthreads();
    xsum_part[((size_t)b * XP_ + ch) * D_ + t] =
        ph0red[t] + ph0red[256 + t] + ph0red[512 + t] + ph0red[768 + t];
    #pragma unroll
    for (int k = 0; k < 2; ++k) {
      y1[(size_t)b * (N_ * D_) + ch * 512 + k * 256 + t] = 0.f;
      y2[(size_t)b * (N_ * D_) + ch * 512 + k * 256 + t] = 0.f;
    }
  }
  arrive(c0);
  wait16(c0);

  // ---- small0: s1=(1/N)xsum@W -> v1 -> t1 (2 n-units per block) ----
  {
    float a = 0.f;
    #pragma unroll
    for (int p = 0; p < XP_; ++p) a += xsum_part[((size_t)b * XP_ + p) * D_ + t];
    __syncthreads();  // ph0red (aliased region) fully consumed before zloc write
    zloc[t] = a;
    __syncthreads();
    small_one(b, ch * 2, W, 1.f / 32.f, 0, 0, t_fp, t_bhi, t_blo, nullptr,
              zloc, sq_red, v_lds);
    small_one(b, ch * 2 + 1, W, 1.f / 32.f, 0, 0, t_fp, t_bhi, t_blo, nullptr,
              zloc, sq_red, v_lds);
  }
  arrive(ct1);
  wait16(ct1);

  // ---- pass 1: y1 += c2^T @ x ----
  pass_phase(b, t_bhi, t_blo, y1, x_lds, c_Th, c_Tl);
  arrive(cy1);
  wait16(cy1);

  // ---- small1: s2=y1@W -> v2 -> t12 = t1 + W@v2 ----
  #pragma unroll
  for (int u = 0; u < 2; ++u) {
    int n = ch * 2 + u;
    zloc[t] = y1[((size_t)b * N_ + n) * D_ + t];
    __syncthreads();
    small_one(b, n, W, 1.f, 1, 0, t_fp, t_bhi, t_blo, nullptr,
              zloc, sq_red, v_lds);
  }
  arrive(ct2);
  wait16(ct2);

  // ---- pass 2: y2 += c3^T @ x ----
  pass_phase(b, t_bhi, t_blo, y2, x_lds, c_Th, c_Tl);
  arrive(cy2);
  wait16(cy2);

  // ---- small2: s3=y2@W -> squash -> out ----
  #pragma unroll
  for (int u = 0; u < 2; ++u) {
    int n = ch * 2 + u;
    zloc[t] = y2[((size_t)b * N_ + n) * D_ + t];
    __syncthreads();
    small_one(b, n, W, 1.f, 0, 1, t_fp, t_bhi, t_blo, out,
              zloc, sq_red, v_lds);
  }
}

extern "C" void kernel_launch(void* const* d_in, const int* in_sizes, int n_in,
                              void* d_out, int out_size, void* d_ws, size_t ws_size,
                              hipStream_t stream) {
  const float* x = (const float*)d_in[0];   // [B,S,D] fp32
  const float* W = (const float*)d_in[1];   // [N,D,C] fp32
  float* out = (float*)d_out;               // [B,N,C] fp32

  // ws (~4.5 MB): [xsum_part 512K | y1 1M | y2 1M | t_fp 1M | t_bhi 512K | t_blo 512K | cnt 640B]
  char* ws = (char*)d_ws;
  float* xsum_part = (float*)ws;
  float* y1 = (float*)(ws + 524288);
  float* y2 = y1 + B_ * N_ * D_;
  float* t_fp = y2 + B_ * N_ * D_;
  __bf16* t_bhi = (__bf16*)(t_fp + B_ * N_ * D_);
  __bf16* t_blo = t_bhi + B_ * N_ * D_;
  int* cnt = (int*)(t_blo + B_ * N_ * D_);

  hipMemsetAsync(cnt, 0, 5 * 32 * sizeof(int), stream);
  k_fused<<<dim3(B_ * XP_), dim3(256), 0, stream>>>(
      x, W, xsum_part, y1, y2, t_fp, t_bhi, t_blo, cnt, out);
}

// Round 9
// 191.796 us; speedup vs baseline: 1.6234x; 1.6234x over previous
//
#include <hip/hip_runtime.h>
#include <math.h>

namespace {
constexpr int B_ = 32, S_ = 1024, D_ = 256, N_ = 32, C_ = 64;
constexpr int NC_ = N_ * C_;  // 2048
constexpr int XP_ = 16;       // chunks (and xsum partials) per b
constexpr int CPAD_ = 64;     // counter padding (ints) -> 256 B per counter

typedef __bf16 bf16x8 __attribute__((ext_vector_type(8)));
typedef __bf16 bf16x4 __attribute__((ext_vector_type(4)));
typedef float floatx4 __attribute__((ext_vector_type(4)));

constexpr int XS_ = 264;  // x_lds row stride
constexpr int CS_ = 72;   // c_T row stride (s 64 + 8 pad)
}  // namespace

// ---- per-b producer/consumer sync (device-scope, XCD-safe) ----
// arrive: RELEASE increment after __syncthreads (writes drained).
// wait16: RELAXED polling (no per-poll cache invalidate!), one ACQUIRE at exit.
__device__ __forceinline__ void arrive(int* p) {
  __syncthreads();
  if (threadIdx.x == 0)
    __hip_atomic_fetch_add(p, 1, __ATOMIC_RELEASE, __HIP_MEMORY_SCOPE_AGENT);
}
__device__ __forceinline__ void wait16(int* p) {
  if (threadIdx.x == 0) {
    while (__hip_atomic_load(p, __ATOMIC_RELAXED, __HIP_MEMORY_SCOPE_AGENT) < 16)
      __builtin_amdgcn_s_sleep(8);
    (void)__hip_atomic_load(p, __ATOMIC_ACQUIRE, __HIP_MEMORY_SCOPE_AGENT);
  }
  __syncthreads();
}

// ---- one (b,n) small unit; zloc (256 fl) preloaded in LDS ----
__device__ __forceinline__ void small_one(
    int b, int n, const float* __restrict__ W, float scale, int accum,
    int final_, float* __restrict__ t_fp, __bf16* __restrict__ t_bhi,
    __bf16* __restrict__ t_blo, float* __restrict__ out,
    const float* zloc, float* sq_red, float* v_lds) {
  const int t = threadIdx.x;
  const int c = t & 63, dq = t >> 6;
  const float* Wn = W + (size_t)n * (D_ * C_);
  float s = 0.f;
  #pragma unroll 8
  for (int dd = 0; dd < 64; ++dd) {
    int d = dq * 64 + dd;
    s += zloc[d] * Wn[d * 64 + c];
  }
  sq_red[dq * 64 + c] = s;
  __syncthreads();
  if (t < 64) {
    float sc = (sq_red[t] + sq_red[64 + t] + sq_red[128 + t] + sq_red[192 + t]) * scale;
    float sq = sc * sc;
    #pragma unroll
    for (int m = 1; m <= 32; m <<= 1) sq += __shfl_xor(sq, m);
    float scl = sq / ((1.f + sq) * sqrtf(sq + 1e-8f));
    float v = sc * scl;
    v_lds[t] = v;
    if (final_) out[(size_t)b * NC_ + n * 64 + t] = v;
  }
  __syncthreads();
  if (!final_) {
    const float4* W4 = (const float4*)Wn + t * 16;
    float acc = 0.f;
    #pragma unroll
    for (int q = 0; q < 16; ++q) {
      float4 wv = W4[q];
      acc += wv.x * v_lds[q * 4] + wv.y * v_lds[q * 4 + 1] +
             wv.z * v_lds[q * 4 + 2] + wv.w * v_lds[q * 4 + 3];
    }
    size_t idx = ((size_t)b * N_ + n) * D_ + t;
    float tf = acc + (accum ? t_fp[idx] : 0.f);
    t_fp[idx] = tf;
    __bf16 hi = (__bf16)tf;
    t_bhi[idx] = hi;
    t_blo[idx] = (__bf16)(tf - (float)hi);
  }
  __syncthreads();
}

// ---- routing pass: agr = x.t (t hi/lo from global/L2) -> softmax -> y += c^T@x ----
__device__ __forceinline__ void pass_phase(
    int b, const __bf16* __restrict__ t_bhi, const __bf16* __restrict__ t_blo,
    float* __restrict__ y, const __bf16* x_lds, __bf16* c_Th, __bf16* c_Tl) {
  const int t = threadIdx.x, w = t >> 6, lane = t & 63;
  const int quad = lane >> 4, l16 = lane & 15;
  const __bf16* tb_h = t_bhi + (size_t)b * 8192;
  const __bf16* tb_l = t_blo + (size_t)b * 8192;

  floatx4 acc[2];
  acc[0] = (floatx4){0.f, 0.f, 0.f, 0.f};
  acc[1] = (floatx4){0.f, 0.f, 0.f, 0.f};
  const int sbase = w * 16;
  #pragma unroll
  for (int k0 = 0; k0 < 256; k0 += 32) {
    int ks = k0 + quad * 8;
    bf16x8 bfrag = *(const bf16x8*)(x_lds + (sbase + l16) * XS_ + ks);
    #pragma unroll
    for (int i = 0; i < 2; ++i) {
      bf16x8 ah = *(const bf16x8*)(tb_h + (i * 16 + l16) * 256 + ks);
      bf16x8 al = *(const bf16x8*)(tb_l + (i * 16 + l16) * 256 + ks);
      acc[i] = __builtin_amdgcn_mfma_f32_16x16x32_bf16(ah, bfrag, acc[i], 0, 0, 0);
      acc[i] = __builtin_amdgcn_mfma_f32_16x16x32_bf16(al, bfrag, acc[i], 0, 0, 0);
    }
  }
  float mx = -1e30f;
  #pragma unroll
  for (int i = 0; i < 2; ++i)
    #pragma unroll
    for (int r = 0; r < 4; ++r) mx = fmaxf(mx, acc[i][r]);
  mx = fmaxf(mx, __shfl_xor(mx, 16));
  mx = fmaxf(mx, __shfl_xor(mx, 32));
  float e_[2][4];
  float ss = 0.f;
  #pragma unroll
  for (int i = 0; i < 2; ++i)
    #pragma unroll
    for (int r = 0; r < 4; ++r) { e_[i][r] = __expf(acc[i][r] - mx); ss += e_[i][r]; }
  ss += __shfl_xor(ss, 16);
  ss += __shfl_xor(ss, 32);
  float inv = 1.f / ss;
  #pragma unroll
  for (int i = 0; i < 2; ++i)
    #pragma unroll
    for (int r = 0; r < 4; ++r) {
      float cv = e_[i][r] * inv;
      __bf16 chi = (__bf16)cv;
      int o = (i * 16 + quad * 4 + r) * CS_ + sbase + l16;
      c_Th[o] = chi;
      c_Tl[o] = (__bf16)(cv - (float)chi);
    }
  __syncthreads();

  floatx4 acc2[2][4];
  #pragma unroll
  for (int i = 0; i < 2; ++i)
    #pragma unroll
    for (int dt = 0; dt < 4; ++dt) acc2[i][dt] = (floatx4){0.f, 0.f, 0.f, 0.f};
  const int dbase = w * 64;
  #pragma unroll
  for (int k0 = 0; k0 < 64; k0 += 32) {
    int ks = k0 + quad * 8;
    bf16x8 ah[2], al[2];
    #pragma unroll
    for (int i = 0; i < 2; ++i) {
      ah[i] = *(const bf16x8*)(c_Th + (i * 16 + l16) * CS_ + ks);
      al[i] = *(const bf16x8*)(c_Tl + (i * 16 + l16) * CS_ + ks);
    }
    #pragma unroll
    for (int dt = 0; dt < 4; ++dt) {
      bf16x8 bfr;
      #pragma unroll
      for (int j8 = 0; j8 < 8; ++j8)
        bfr[j8] = x_lds[(ks + j8) * XS_ + dbase + dt * 16 + l16];
      #pragma unroll
      for (int i = 0; i < 2; ++i) {
        acc2[i][dt] = __builtin_amdgcn_mfma_f32_16x16x32_bf16(ah[i], bfr, acc2[i][dt], 0, 0, 0);
        acc2[i][dt] = __builtin_amdgcn_mfma_f32_16x16x32_bf16(al[i], bfr, acc2[i][dt], 0, 0, 0);
      }
    }
  }
  #pragma unroll
  for (int i = 0; i < 2; ++i)
    #pragma unroll
    for (int dt = 0; dt < 4; ++dt)
      #pragma unroll
      for (int r = 0; r < 4; ++r) {
        int n = i * 16 + quad * 4 + r;
        int d = dbase + dt * 16 + l16;
        atomicAdd(&y[((size_t)b * N_ + n) * D_ + d], acc2[i][dt][r]);
      }
  __syncthreads();
}

// ---- whole pipeline, one launch: 512 blocks = (b, ch); per-b sync only ----
extern "C" __global__ __launch_bounds__(256) void k_fused(
    const float* __restrict__ x, const float* __restrict__ W,
    float* __restrict__ xsum_part, float* __restrict__ y1,
    float* __restrict__ y2, float* __restrict__ t_fp,
    __bf16* __restrict__ t_bhi, __bf16* __restrict__ t_blo,
    int* __restrict__ cnt, float* __restrict__ out) {
  __shared__ __align__(16) __bf16 x_lds[64 * XS_];  // 33,792 B, lives all phases
  __shared__ __align__(16) __bf16 c_Th[N_ * CS_];   //  4,608 B
  __shared__ __align__(16) __bf16 c_Tl[N_ * CS_];   //  4,608 B  (total 43,008)
  float* zloc = (float*)c_Th;          // aliases, used only in small phases
  float* sq_red = (float*)c_Th + 256;
  float* v_lds = (float*)c_Th + 512;
  float* ph0red = (float*)c_Tl;        // 4 KB, ph0 only

  const int bidx = blockIdx.x;
  const int b = bidx >> 4, ch = bidx & 15;
  const int t = threadIdx.x;
  // one padded counter per (phase, b): 256 B apart
  int* c0 = cnt + (0 * 32 + b) * CPAD_;   // ph0 done
  int* ct1 = cnt + (1 * 32 + b) * CPAD_;  // t1 ready
  int* cy1 = cnt + (2 * 32 + b) * CPAD_;  // y1 done
  int* ct2 = cnt + (3 * 32 + b) * CPAD_;  // t12 ready
  int* cy2 = cnt + (4 * 32 + b) * CPAD_;  // y2 done

  // ---- ph0: stage x chunk -> LDS bf16, xsum partial, zero y1/y2 slices ----
  {
    const float* xb = x + ((size_t)b * S_ + ch * 64) * D_;
    float xp[4] = {0.f, 0.f, 0.f, 0.f};
    #pragma unroll
    for (int i = 0; i < 16; ++i) {
      int pos = i * 1024 + t * 4;
      int row = pos >> 8, col = (t & 63) * 4;
      float4 f = *(const float4*)(xb + pos);
      bf16x4 p4;
      p4[0] = (__bf16)f.x; p4[1] = (__bf16)f.y;
      p4[2] = (__bf16)f.z; p4[3] = (__bf16)f.w;
      *(bf16x4*)(x_lds + row * XS_ + col) = p4;
      xp[0] += f.x; xp[1] += f.y; xp[2] += f.z; xp[3] += f.w;
    }
    const int w = t >> 6, col = (t & 63) * 4;
    #pragma unroll
    for (int k = 0; k < 4; ++k) ph0red[w * 256 + col + k] = xp[k];
    __syncthreads();
    xsum_part[((size_t)b * XP_ + ch) * D_ + t] =
        ph0red[t] + ph0red[256 + t] + ph0red[512 + t] + ph0red[768 + t];
    #pragma unroll
    for (int k = 0; k < 2; ++k) {
      y1[(size_t)b * (N_ * D_) + ch * 512 + k * 256 + t] = 0.f;
      y2[(size_t)b * (N_ * D_) + ch * 512 + k * 256 + t] = 0.f;
    }
  }
  arrive(c0);
  wait16(c0);

  // ---- small0: s1=(1/N)xsum@W -> v1 -> t1 (2 n-units per block) ----
  {
    float a = 0.f;
    #pragma unroll
    for (int p = 0; p < XP_; ++p) a += xsum_part[((size_t)b * XP_ + p) * D_ + t];
    __syncthreads();  // ph0red (aliased region) fully consumed before zloc write
    zloc[t] = a;
    __syncthreads();
    small_one(b, ch * 2, W, 1.f / 32.f, 0, 0, t_fp, t_bhi, t_blo, nullptr,
              zloc, sq_red, v_lds);
    small_one(b, ch * 2 + 1, W, 1.f / 32.f, 0, 0, t_fp, t_bhi, t_blo, nullptr,
              zloc, sq_red, v_lds);
  }
  arrive(ct1);
  wait16(ct1);

  // ---- pass 1: y1 += c2^T @ x ----
  pass_phase(b, t_bhi, t_blo, y1, x_lds, c_Th, c_Tl);
  arrive(cy1);
  wait16(cy1);

  // ---- small1: s2=y1@W -> v2 -> t12 = t1 + W@v2 ----
  #pragma unroll
  for (int u = 0; u < 2; ++u) {
    int n = ch * 2 + u;
    zloc[t] = y1[((size_t)b * N_ + n) * D_ + t];
    __syncthreads();
    small_one(b, n, W, 1.f, 1, 0, t_fp, t_bhi, t_blo, nullptr,
              zloc, sq_red, v_lds);
  }
  arrive(ct2);
  wait16(ct2);

  // ---- pass 2: y2 += c3^T @ x ----
  pass_phase(b, t_bhi, t_blo, y2, x_lds, c_Th, c_Tl);
  arrive(cy2);
  wait16(cy2);

  // ---- small2: s3=y2@W -> squash -> out ----
  #pragma unroll
  for (int u = 0; u < 2; ++u) {
    int n = ch * 2 + u;
    zloc[t] = y2[((size_t)b * N_ + n) * D_ + t];
    __syncthreads();
    small_one(b, n, W, 1.f, 0, 1, t_fp, t_bhi, t_blo, out,
              zloc, sq_red, v_lds);
  }
}

extern "C" void kernel_launch(void* const* d_in, const int* in_sizes, int n_in,
                              void* d_out, int out_size, void* d_ws, size_t ws_size,
                              hipStream_t stream) {
  const float* x = (const float*)d_in[0];   // [B,S,D] fp32
  const float* W = (const float*)d_in[1];   // [N,D,C] fp32
  float* out = (float*)d_out;               // [B,N,C] fp32

  // ws (~4.6 MB): [xsum_part 512K | y1 1M | y2 1M | t_fp 1M | t_bhi 512K | t_blo 512K | cnt 40K]
  char* ws = (char*)d_ws;
  float* xsum_part = (float*)ws;
  float* y1 = (float*)(ws + 524288);
  float* y2 = y1 + B_ * N_ * D_;
  float* t_fp = y2 + B_ * N_ * D_;
  __bf16* t_bhi = (__bf16*)(t_fp + B_ * N_ * D_);
  __bf16* t_blo = t_bhi + B_ * N_ * D_;
  int* cnt = (int*)(t_blo + B_ * N_ * D_);

  hipMemsetAsync(cnt, 0, 5 * 32 * CPAD_ * sizeof(int), stream);
  k_fused<<<dim3(B_ * XP_), dim3(256), 0, stream>>>(
      x, W, xsum_part, y1, y2, t_fp, t_bhi, t_blo, cnt, out);
}

// Round 10
// 158.230 us; speedup vs baseline: 1.9678x; 1.2121x over previous
//
#include <hip/hip_runtime.h>
#include <math.h>

namespace {
constexpr int B_ = 32, S_ = 1024, D_ = 256, N_ = 32, C_ = 64;
constexpr int NC_ = N_ * C_;  // 2048
constexpr int XP_ = 16;       // xsum partials / s-chunks per b

typedef __bf16 bf16x8 __attribute__((ext_vector_type(8)));
typedef __bf16 bf16x4 __attribute__((ext_vector_type(4)));
typedef float floatx4 __attribute__((ext_vector_type(4)));

constexpr int XS_ = 264;  // x_lds row stride
constexpr int TS_ = 264;  // t_lds row stride
constexpr int CS_ = 72;   // c_T row stride (s 64 + 8 pad)
}  // namespace

// K1: per (b, s-chunk): ONE float4 sweep over x -> bf16 staging + xsum partial.
extern "C" __global__ __launch_bounds__(256) void k_stage(
    const float* __restrict__ x, float* __restrict__ xsum_part,
    __bf16* __restrict__ xb_ws) {
  __shared__ float red[1024];
  const int b = blockIdx.x, sb = blockIdx.y, t = threadIdx.x;
  const float* xb = x + ((size_t)b * S_ + sb * 64) * D_;
  __bf16* xo = xb_ws + ((size_t)(b * XP_ + sb)) * (64 * D_);

  float xp[4] = {0.f, 0.f, 0.f, 0.f};
  #pragma unroll
  for (int i = 0; i < 16; ++i) {
    int pos = i * 1024 + t * 4;   // row = pos>>8 advances; col = (t&63)*4 fixed
    float4 f = *(const float4*)(xb + pos);
    bf16x4 p4;
    p4[0] = (__bf16)f.x; p4[1] = (__bf16)f.y;
    p4[2] = (__bf16)f.z; p4[3] = (__bf16)f.w;
    *(bf16x4*)(xo + pos) = p4;
    xp[0] += f.x; xp[1] += f.y; xp[2] += f.z; xp[3] += f.w;
  }
  const int w = t >> 6, col = (t & 63) * 4;
  #pragma unroll
  for (int k = 0; k < 4; ++k) red[w * 256 + col + k] = xp[k];
  __syncthreads();
  xsum_part[((size_t)b * XP_ + sb) * D_ + t] =
      red[t] + red[256 + t] + red[512 + t] + red[768 + t];
}

// K2 (small chain) per (b,n):
//   zloc[d] = sum_p z[...]  (P partials; P=1 for direct y rows)
//   s[c] = scale * zloc@W[n];  v = squash(s)
//   final: write v to vout;  else: t = W[n]@v (+= old t if accum) -> fp32 + bf16 hi/lo
//   yzero: zero this block's 256-float row of the NEXT pass's y accumulator.
extern "C" __global__ __launch_bounds__(256) void k_small(
    const float* __restrict__ z, const float* __restrict__ W,
    float* __restrict__ t_fp, __bf16* __restrict__ t_bhi,
    __bf16* __restrict__ t_blo, float* __restrict__ vout,
    float* __restrict__ yzero,
    int P, int zb, int zp, int zn, float scale, int accum, int final_) {
  __shared__ float zloc[256];
  __shared__ float sq_red[4][64];
  __shared__ float v_lds[64];
  const int b = blockIdx.x, n = blockIdx.y, t = threadIdx.x;

  float a = 0.f;
  for (int p = 0; p < P; ++p) a += z[(size_t)b * zb + (size_t)p * zp + n * zn + t];
  zloc[t] = a;
  if (yzero) yzero[((size_t)b * N_ + n) * D_ + t] = 0.f;
  __syncthreads();

  const int c = t & 63, dq = t >> 6;
  const float* Wn = W + (size_t)n * (D_ * C_);
  float s = 0.f;
  #pragma unroll 8
  for (int dd = 0; dd < 64; ++dd) {
    int d = dq * 64 + dd;
    s += zloc[d] * Wn[d * 64 + c];
  }
  sq_red[dq][c] = s;
  __syncthreads();

  if (t < 64) {
    float sc = (sq_red[0][t] + sq_red[1][t] + sq_red[2][t] + sq_red[3][t]) * scale;
    float sq = sc * sc;
    #pragma unroll
    for (int m = 1; m <= 32; m <<= 1) sq += __shfl_xor(sq, m);
    float scl = sq / ((1.f + sq) * sqrtf(sq + 1e-8f));
    float v = sc * scl;
    v_lds[t] = v;
    if (final_) vout[(size_t)b * NC_ + n * 64 + t] = v;
  }
  __syncthreads();

  if (!final_) {
    const float4* W4 = (const float4*)Wn + t * 16;
    float acc = 0.f;
    #pragma unroll
    for (int q = 0; q < 16; ++q) {
      float4 wv = W4[q];
      acc += wv.x * v_lds[q * 4] + wv.y * v_lds[q * 4 + 1] +
             wv.z * v_lds[q * 4 + 2] + wv.w * v_lds[q * 4 + 3];
    }
    size_t idx = ((size_t)b * N_ + n) * D_ + t;
    float tf = acc + (accum ? t_fp[idx] : 0.f);
    t_fp[idx] = tf;
    __bf16 hi = (__bf16)tf;
    t_bhi[idx] = hi;
    t_blo[idx] = (__bf16)(tf - (float)hi);
  }
}

// K3 (routing pass) per (b, s-chunk of 64):
//   agr[s,n] = x.t via MFMA (t bf16 hi+lo) -> softmax over n ->
//   y[b,n,d] += c^T @ x via MFMA (c bf16 hi+lo), fp32 atomics.
extern "C" __global__ __launch_bounds__(256) void k_pass(
    const __bf16* __restrict__ xb_ws, const __bf16* __restrict__ t_bhi,
    const __bf16* __restrict__ t_blo, float* __restrict__ y) {
  __shared__ __align__(16) __bf16 x_lds[64 * XS_];
  __shared__ __align__(16) __bf16 th_lds[N_ * TS_];
  __shared__ __align__(16) __bf16 tl_lds[N_ * TS_];
  __shared__ __align__(16) __bf16 c_Th[N_ * CS_];
  __shared__ __align__(16) __bf16 c_Tl[N_ * CS_];
  const int b = blockIdx.x, ch = blockIdx.y;
  const int t = threadIdx.x, w = t >> 6, lane = t & 63;
  const int quad = lane >> 4, l16 = lane & 15;

  // stage t hi/lo (8192 bf16 each, per b)
  #pragma unroll
  for (int e = 0; e < 4; ++e) {
    int idx = e * 2048 + t * 8;
    int n = idx >> 8, d = idx & 255;
    *(uint4*)(th_lds + n * TS_ + d) = *(const uint4*)(t_bhi + (size_t)b * 8192 + idx);
    *(uint4*)(tl_lds + n * TS_ + d) = *(const uint4*)(t_blo + (size_t)b * 8192 + idx);
  }
  // stage x (already bf16 in ws)
  const __bf16* xsrc = xb_ws + ((size_t)(b * XP_ + ch)) * (64 * D_);
  #pragma unroll
  for (int e = 0; e < 8; ++e) {
    int idx = e * 2048 + t * 8;
    int row = idx >> 8, col = idx & 255;
    *(uint4*)(x_lds + row * XS_ + col) = *(const uint4*)(xsrc + idx);
  }
  __syncthreads();

  // agreement GEMM: A=t (m=n), B=x (n'=s), K=256; wave w owns s-tile w*16
  floatx4 acc[2];
  acc[0] = (floatx4){0.f, 0.f, 0.f, 0.f};
  acc[1] = (floatx4){0.f, 0.f, 0.f, 0.f};
  const int sbase = w * 16;
  #pragma unroll
  for (int k0 = 0; k0 < 256; k0 += 32) {
    int ks = k0 + quad * 8;
    bf16x8 bfrag = *(const bf16x8*)(x_lds + (sbase + l16) * XS_ + ks);
    #pragma unroll
    for (int i = 0; i < 2; ++i) {
      bf16x8 ah = *(const bf16x8*)(th_lds + (i * 16 + l16) * TS_ + ks);
      bf16x8 al = *(const bf16x8*)(tl_lds + (i * 16 + l16) * TS_ + ks);
      acc[i] = __builtin_amdgcn_mfma_f32_16x16x32_bf16(ah, bfrag, acc[i], 0, 0, 0);
      acc[i] = __builtin_amdgcn_mfma_f32_16x16x32_bf16(al, bfrag, acc[i], 0, 0, 0);
    }
  }
  // softmax over n for s = sbase + l16
  float mx = -1e30f;
  #pragma unroll
  for (int i = 0; i < 2; ++i)
    #pragma unroll
    for (int r = 0; r < 4; ++r) mx = fmaxf(mx, acc[i][r]);
  mx = fmaxf(mx, __shfl_xor(mx, 16));
  mx = fmaxf(mx, __shfl_xor(mx, 32));
  float e_[2][4];
  float ss = 0.f;
  #pragma unroll
  for (int i = 0; i < 2; ++i)
    #pragma unroll
    for (int r = 0; r < 4; ++r) { e_[i][r] = __expf(acc[i][r] - mx); ss += e_[i][r]; }
  ss += __shfl_xor(ss, 16);
  ss += __shfl_xor(ss, 32);
  float inv = 1.f / ss;
  #pragma unroll
  for (int i = 0; i < 2; ++i)
    #pragma unroll
    for (int r = 0; r < 4; ++r) {
      float cv = e_[i][r] * inv;
      __bf16 chi = (__bf16)cv;
      int o = (i * 16 + quad * 4 + r) * CS_ + sbase + l16;
      c_Th[o] = chi;
      c_Tl[o] = (__bf16)(cv - (float)chi);
    }
  __syncthreads();

  // y GEMM: y[n,d] += c^T @ x; wave w owns d-range w*64
  floatx4 acc2[2][4];
  #pragma unroll
  for (int i = 0; i < 2; ++i)
    #pragma unroll
    for (int dt = 0; dt < 4; ++dt) acc2[i][dt] = (floatx4){0.f, 0.f, 0.f, 0.f};
  const int dbase = w * 64;
  #pragma unroll
  for (int k0 = 0; k0 < 64; k0 += 32) {
    int ks = k0 + quad * 8;
    bf16x8 ah[2], al[2];
    #pragma unroll
    for (int i = 0; i < 2; ++i) {
      ah[i] = *(const bf16x8*)(c_Th + (i * 16 + l16) * CS_ + ks);
      al[i] = *(const bf16x8*)(c_Tl + (i * 16 + l16) * CS_ + ks);
    }
    #pragma unroll
    for (int dt = 0; dt < 4; ++dt) {
      bf16x8 bfr;
      #pragma unroll
      for (int j8 = 0; j8 < 8; ++j8)
        bfr[j8] = x_lds[(ks + j8) * XS_ + dbase + dt * 16 + l16];
      #pragma unroll
      for (int i = 0; i < 2; ++i) {
        acc2[i][dt] = __builtin_amdgcn_mfma_f32_16x16x32_bf16(ah[i], bfr, acc2[i][dt], 0, 0, 0);
        acc2[i][dt] = __builtin_amdgcn_mfma_f32_16x16x32_bf16(al[i], bfr, acc2[i][dt], 0, 0, 0);
      }
    }
  }
  #pragma unroll
  for (int i = 0; i < 2; ++i)
    #pragma unroll
    for (int dt = 0; dt < 4; ++dt)
      #pragma unroll
      for (int r = 0; r < 4; ++r) {
        int n = i * 16 + quad * 4 + r;
        int d = dbase + dt * 16 + l16;
        atomicAdd(&y[((size_t)b * N_ + n) * D_ + d], acc2[i][dt][r]);
      }
}

extern "C" void kernel_launch(void* const* d_in, const int* in_sizes, int n_in,
                              void* d_out, int out_size, void* d_ws, size_t ws_size,
                              hipStream_t stream) {
  const float* x = (const float*)d_in[0];   // [B,S,D] fp32
  const float* W = (const float*)d_in[1];   // [N,D,C] fp32
  float* out = (float*)d_out;               // [B,N,C] fp32

  // ws (~21 MB): [xb_ws 16M | xsum_part 512K | y1 1M | y2 1M | t_fp 1M | t_bhi 512K | t_blo 512K]
  char* ws = (char*)d_ws;
  __bf16* xb_ws = (__bf16*)ws;
  float* xsum_part = (float*)(ws + 16777216);
  float* y1 = (float*)(ws + 16777216 + 524288);
  float* y2 = y1 + B_ * N_ * D_;
  float* t_fp = y2 + B_ * N_ * D_;
  __bf16* t_bhi = (__bf16*)(t_fp + B_ * N_ * D_);
  __bf16* t_blo = t_bhi + B_ * N_ * D_;

  // 1) single-sweep stage: x -> bf16 ws + xsum partials
  k_stage<<<dim3(B_, XP_), 256, 0, stream>>>(x, xsum_part, xb_ws);

  // 2) iter 0: s1=(1/N)xsum@W -> v1 -> t1; zero y1
  k_small<<<dim3(B_, N_), 256, 0, stream>>>(
      xsum_part, W, t_fp, t_bhi, t_blo, nullptr, y1,
      XP_, XP_ * D_, D_, 0, 1.f / 32.f, 0, 0);

  // 3) pass 1: y1 += c2^T @ x
  k_pass<<<dim3(B_, XP_), 256, 0, stream>>>(xb_ws, t_bhi, t_blo, y1);

  // 4) s2=y1@W -> v2 -> t12 = t1 + W@v2; zero y2
  k_small<<<dim3(B_, N_), 256, 0, stream>>>(
      y1, W, t_fp, t_bhi, t_blo, nullptr, y2,
      1, N_ * D_, 0, D_, 1.f, 1, 0);

  // 5) pass 2: y2 += c3^T @ x
  k_pass<<<dim3(B_, XP_), 256, 0, stream>>>(xb_ws, t_bhi, t_blo, y2);

  // 6) s3=y2@W -> squash -> out
  k_small<<<dim3(B_, N_), 256, 0, stream>>>(
      y2, W, t_fp, t_bhi, t_blo, out, nullptr,
      1, N_ * D_, 0, D_, 1.f, 0, 1);
}